// Round 5
// baseline (520.264 us; speedup 1.0000x reference)
//
#include <hip/hip_runtime.h>
#include <hip/hip_bf16.h>
#include <stdint.h>

#define NE   64
#define DIM  1024
#define HID  512
#define TPE  1024   // tokens per expert (uniform in this problem)

typedef __attribute__((ext_vector_type(8)))  __bf16          bf16x8;
typedef __attribute__((ext_vector_type(16))) float           f32x16;
typedef __attribute__((ext_vector_type(8)))  unsigned short  ushort8_t;
typedef __attribute__((ext_vector_type(4)))  float           float4_t;

__device__ __forceinline__ unsigned short f2bf(float f) {
  return __builtin_bit_cast(unsigned short, static_cast<__bf16>(f));  // RNE
}
__device__ __forceinline__ float bf2f(unsigned short u) {
  unsigned int x = ((unsigned int)u) << 16;
  return __builtin_bit_cast(float, x);
}
__device__ __forceinline__ ushort8_t pack8(float4_t a, float4_t b) {
  ushort8_t r;
  r[0] = f2bf(a[0]); r[1] = f2bf(a[1]); r[2] = f2bf(a[2]); r[3] = f2bf(a[3]);
  r[4] = f2bf(b[0]); r[5] = f2bf(b[1]); r[6] = f2bf(b[2]); r[7] = f2bf(b[3]);
  return r;
}
__device__ __forceinline__ bf16x8 ldsfrag(const unsigned short* p) {
  return __builtin_bit_cast(bf16x8, *reinterpret_cast<const ushort8_t*>(p));
}

// Raw barrier: ds_writes committed (lgkmcnt 0) but global loads stay IN FLIGHT
// across the barrier (no vmcnt drain — the whole point vs __syncthreads).
__device__ __forceinline__ void barrier_lgkm() {
  asm volatile("s_waitcnt lgkmcnt(0)" ::: "memory");
  __builtin_amdgcn_s_barrier();
}

// LDS row stride 40 bf16 (80 B): 16B-granule g = 5*row + k16; frag reads
// (row=base+(lane&31), k16=lane>>5) hit each of 8 bank-groups 8x/wave.
#define LDK 40

// XCD-aware bijective swizzle (grid % 8 == 0): contiguous chunk per XCD.
__device__ __forceinline__ int xcd_swizzle(int bid, int nwg) {
  return (bid & 7) * (nwg >> 3) + (bid >> 3);
}

// ---------------------------------------------------------------------------
// Phase 1: H = bf16( silu(X@W1^T) * (X@W3^T) ), per expert.
// BM=128 x BN=64, BK=32, 4 waves (2Mx2N) of 64x32-dual, 32x32x16 frags.
// Per wave-kt: 8 ds_read_b128 (96cy) -> 8 MFMA (64cy): 67% duty ceiling.
// Depth-2 reg prefetch + raw barriers: loads issued at kt consumed at kt+2
// (~2 iters ~550cy cover). LDS 40KB dbuf; ~160 regs -> ~12 waves/CU.
// ---------------------------------------------------------------------------
#define P1_NKT (DIM / 32)

__global__ __launch_bounds__(256, 3) void p1_kernel(
    const float* __restrict__ X, const float* __restrict__ W1,
    const float* __restrict__ W3, unsigned short* __restrict__ H) {
  __shared__ __align__(16) unsigned short lA [2][128 * LDK];  // 20480 B
  __shared__ __align__(16) unsigned short lB1[2][ 64 * LDK];  // 10240 B
  __shared__ __align__(16) unsigned short lB3[2][ 64 * LDK];  // 10240 B

  const int tile = xcd_swizzle(blockIdx.x, NE * 8 * 8);
  const int e  = tile >> 6;
  const int tn = (tile >> 3) & 7;    // 8 hid tiles of 64
  const int tm = tile & 7;           // inner: W1/W3 slabs stay L2-hot
  const int t  = threadIdx.x;

  const float* gA  = X  + (size_t)(e * TPE + tm * 128) * DIM;
  const float* gB1 = W1 + ((size_t)e * HID + tn * 64) * DIM;
  const float* gB3 = W3 + ((size_t)e * HID + tn * 64) * DIM;

  // chunks of 8 consecutive floats; adjacent lanes -> adjacent 32B (coalesced).
  // A: 128x32 = 512 chunks/256thr = 2 (row ar+64i); B: 64x32 = 1 chunk (row ar)
  const int ar = t >> 2, ac = (t & 3) * 8;

  // depth-2: two named register sets (static indexing, rule #20)
  float4_t a0[2][2], b10[2], b30[2];
  float4_t a1[2][2], b11[2], b31[2];

  auto load_g = [&](float4_t (&a)[2][2], float4_t (&b1)[2], float4_t (&b3)[2],
                    int kt) {
#pragma unroll
    for (int i = 0; i < 2; ++i) {
      const size_t o = (size_t)(ar + 64 * i) * DIM + kt * 32 + ac;
      a[i][0] = *reinterpret_cast<const float4_t*>(gA + o);
      a[i][1] = *reinterpret_cast<const float4_t*>(gA + o + 4);
    }
    const size_t ob = (size_t)ar * DIM + kt * 32 + ac;
    b1[0] = *reinterpret_cast<const float4_t*>(gB1 + ob);
    b1[1] = *reinterpret_cast<const float4_t*>(gB1 + ob + 4);
    b3[0] = *reinterpret_cast<const float4_t*>(gB3 + ob);
    b3[1] = *reinterpret_cast<const float4_t*>(gB3 + ob + 4);
  };
  auto store_l = [&](int buf, float4_t (&a)[2][2], float4_t (&b1)[2],
                     float4_t (&b3)[2]) {
#pragma unroll
    for (int i = 0; i < 2; ++i)
      *reinterpret_cast<ushort8_t*>(&lA[buf][(ar + 64 * i) * LDK + ac]) =
          pack8(a[i][0], a[i][1]);
    *reinterpret_cast<ushort8_t*>(&lB1[buf][ar * LDK + ac]) = pack8(b1[0], b1[1]);
    *reinterpret_cast<ushort8_t*>(&lB3[buf][ar * LDK + ac]) = pack8(b3[0], b3[1]);
  };

  const int lane = t & 63;
  const int wv   = t >> 6;
  const int wr   = wv >> 1, wc = wv & 1;   // 2x2 waves: 64M x 32N each
  const int lr   = lane & 31;              // 32x32 frag row/col
  const int ks   = (lane >> 5) * 8;        // k half (8 bf16)

  f32x16 acc1[2], acc3[2];
#pragma unroll
  for (int m = 0; m < 2; ++m)
#pragma unroll
    for (int i = 0; i < 16; ++i) { acc1[m][i] = 0.f; acc3[m][i] = 0.f; }

  auto mfma_phase = [&](int buf) {
#pragma unroll
    for (int kk = 0; kk < 2; ++kk) {       // BK=32 = 2 x K16
      bf16x8 am[2];
#pragma unroll
      for (int m = 0; m < 2; ++m)
        am[m] = ldsfrag(&lA[buf][(wr * 64 + m * 32 + lr) * LDK + kk * 16 + ks]);
      const bf16x8 b1 = ldsfrag(&lB1[buf][(wc * 32 + lr) * LDK + kk * 16 + ks]);
      const bf16x8 b3 = ldsfrag(&lB3[buf][(wc * 32 + lr) * LDK + kk * 16 + ks]);
#pragma unroll
      for (int m = 0; m < 2; ++m) {
        acc1[m] = __builtin_amdgcn_mfma_f32_32x32x16_bf16(am[m], b1, acc1[m], 0, 0, 0);
        acc3[m] = __builtin_amdgcn_mfma_f32_32x32x16_bf16(am[m], b3, acc3[m], 0, 0, 0);
      }
    }
  };

  load_g(a0, b10, b30, 0);
  load_g(a1, b11, b31, 1);
  for (int kt = 0; kt < P1_NKT; kt += 2) {
    // half-iter A: compiler emits COUNTED vmcnt (waits set-0 only; set-1 flies)
    store_l(0, a0, b10, b30);
    if (kt + 2 < P1_NKT) load_g(a0, b10, b30, kt + 2);
    barrier_lgkm();                 // writes visible; NO vmcnt drain
    mfma_phase(0);
    // half-iter B
    store_l(1, a1, b11, b31);
    if (kt + 3 < P1_NKT) load_g(a1, b11, b31, kt + 3);
    barrier_lgkm();
    mfma_phase(1);
  }

  // epilogue: silu(a)*b. 32x32 C/D: col=lane&31, row=(r&3)+8*(r>>2)+4*(lane>>5)
  const int tokBase = e * TPE + tm * 128 + wr * 64;
  const int hid     = tn * 64 + wc * 32 + lr;
  const int ks4     = (lane >> 5) * 4;
#pragma unroll
  for (int m = 0; m < 2; ++m)
#pragma unroll
    for (int r = 0; r < 16; ++r) {
      const int rr  = (r & 3) + 8 * (r >> 2) + ks4;
      const int tok = tokBase + m * 32 + rr;
      const float av = bf2f(f2bf(acc1[m][r]));   // ref bf16 rounding
      const float bv = bf2f(f2bf(acc3[m][r]));
      const float s  = av / (1.0f + __expf(-av));
      H[(size_t)tok * HID + hid] = f2bf(s * bv);
    }
}

// ---------------------------------------------------------------------------
// Phase 2: OUT = fp32( bf16( H @ W2^T ) ), per expert.
// BM=128 x BN=128, BK=32, 4 waves (2x2) of 64x64, 32x32x16 frags.
// Same depth-2 + raw-barrier machinery. LDS 40KB dbuf.
// ---------------------------------------------------------------------------
#define P2_NKT (HID / 32)

__global__ __launch_bounds__(256, 3) void p2_kernel(
    const unsigned short* __restrict__ Hin, const float* __restrict__ W2,
    float* __restrict__ OUT) {
  __shared__ __align__(16) unsigned short lA[2][128 * LDK];  // 20480 B
  __shared__ __align__(16) unsigned short lB[2][128 * LDK];  // 20480 B

  const int tile = xcd_swizzle(blockIdx.x, NE * 8 * 8);
  const int e  = tile >> 6;
  const int tn = (tile >> 3) & 7;    // 8 dim tiles of 128
  const int tm = tile & 7;           // inner: W2 slab L2-hot
  const int t  = threadIdx.x;

  const unsigned short* gA = Hin + (size_t)(e * TPE + tm * 128) * HID;
  const float*          gB = W2  + ((size_t)e * DIM + tn * 128) * HID;

  // A (bf16): 128x32 = one 16-elem chunk/thread: row t>>1, col (t&1)*16
  // B (fp32): 128x32 = two 8-elem chunks/thread: row (t>>2)+64i, col (t&3)*8
  const int arow = t >> 1, acol = (t & 1) * 16;
  const int br = t >> 2, bc = (t & 3) * 8;

  ushort8_t ha0[2], ha1[2];
  float4_t  wb0[2][2], wb1[2][2];

  auto load_g = [&](ushort8_t (&ha)[2], float4_t (&wb)[2][2], int kt) {
    const size_t ao = (size_t)arow * HID + kt * 32 + acol;
    ha[0] = *reinterpret_cast<const ushort8_t*>(gA + ao);
    ha[1] = *reinterpret_cast<const ushort8_t*>(gA + ao + 8);
#pragma unroll
    for (int i = 0; i < 2; ++i) {
      const size_t bo = (size_t)(br + 64 * i) * HID + kt * 32 + bc;
      wb[i][0] = *reinterpret_cast<const float4_t*>(gB + bo);
      wb[i][1] = *reinterpret_cast<const float4_t*>(gB + bo + 4);
    }
  };
  auto store_l = [&](int buf, ushort8_t (&ha)[2], float4_t (&wb)[2][2]) {
    const int ai = arow * LDK + acol;
    *reinterpret_cast<ushort8_t*>(&lA[buf][ai])     = ha[0];
    *reinterpret_cast<ushort8_t*>(&lA[buf][ai + 8]) = ha[1];
#pragma unroll
    for (int i = 0; i < 2; ++i)
      *reinterpret_cast<ushort8_t*>(&lB[buf][(br + 64 * i) * LDK + bc]) =
          pack8(wb[i][0], wb[i][1]);
  };

  const int lane = t & 63;
  const int wv   = t >> 6;
  const int wr   = wv >> 1, wc = wv & 1;   // 2x2 waves, 64x64 each
  const int lr   = lane & 31;
  const int ks   = (lane >> 5) * 8;

  f32x16 acc[2][2];
#pragma unroll
  for (int m = 0; m < 2; ++m)
#pragma unroll
    for (int n = 0; n < 2; ++n)
#pragma unroll
      for (int i = 0; i < 16; ++i) acc[m][n][i] = 0.f;

  auto mfma_phase = [&](int buf) {
#pragma unroll
    for (int kk = 0; kk < 2; ++kk) {
      bf16x8 am[2], bn[2];
#pragma unroll
      for (int m = 0; m < 2; ++m)
        am[m] = ldsfrag(&lA[buf][(wr * 64 + m * 32 + lr) * LDK + kk * 16 + ks]);
#pragma unroll
      for (int n = 0; n < 2; ++n)
        bn[n] = ldsfrag(&lB[buf][(wc * 64 + n * 32 + lr) * LDK + kk * 16 + ks]);
#pragma unroll
      for (int m = 0; m < 2; ++m)
#pragma unroll
        for (int n = 0; n < 2; ++n)
          acc[m][n] = __builtin_amdgcn_mfma_f32_32x32x16_bf16(am[m], bn[n], acc[m][n], 0, 0, 0);
    }
  };

  load_g(ha0, wb0, 0);
  load_g(ha1, wb1, 1);
  for (int kt = 0; kt < P2_NKT; kt += 2) {
    store_l(0, ha0, wb0);
    if (kt + 2 < P2_NKT) load_g(ha0, wb0, kt + 2);
    barrier_lgkm();
    mfma_phase(0);

    store_l(1, ha1, wb1);
    if (kt + 3 < P2_NKT) load_g(ha1, wb1, kt + 3);
    barrier_lgkm();
    mfma_phase(1);
  }

  const int tokBase = e * TPE + tm * 128 + wr * 64;
  const int dBase   = tn * 128 + wc * 64;
  const int ks4     = (lane >> 5) * 4;
#pragma unroll
  for (int m = 0; m < 2; ++m)
#pragma unroll
    for (int n = 0; n < 2; ++n)
#pragma unroll
      for (int r = 0; r < 16; ++r) {
        const int rr  = (r & 3) + 8 * (r >> 2) + ks4;
        const int tok = tokBase + m * 32 + rr;
        const int d   = dBase + n * 32 + lr;
        OUT[(size_t)tok * DIM + d] = bf2f(f2bf(acc[m][n][r]));  // ref bf16->f32
      }
}

// ---------------------------------------------------------------------------
extern "C" void kernel_launch(void* const* d_in, const int* in_sizes, int n_in,
                              void* d_out, int out_size, void* d_ws, size_t ws_size,
                              hipStream_t stream) {
  (void)in_sizes; (void)n_in; (void)out_size; (void)ws_size;
  const float* X  = (const float*)d_in[0];
  const float* W1 = (const float*)d_in[1];
  const float* W2 = (const float*)d_in[2];
  const float* W3 = (const float*)d_in[3];
  // d_in[4] = num_tokens_per_expert: uniform 1024/expert in this problem.

  unsigned short* H = (unsigned short*)d_ws;   // 65536 x 512 bf16 = 64 MiB
  float* OUT = (float*)d_out;

  p1_kernel<<<dim3(NE * 8 * 8), dim3(256), 0, stream>>>(X, W1, W3, H);
  p2_kernel<<<dim3(NE * 8 * 8), dim3(256), 0, stream>>>(H, W2, OUT);
}

// Round 6
// 517.474 us; speedup vs baseline: 1.0054x; 1.0054x over previous
//
#include <hip/hip_runtime.h>
#include <hip/hip_bf16.h>
#include <stdint.h>

#define NE   64
#define DIM  1024
#define HID  512
#define TPE  1024   // tokens per expert (uniform in this problem)

typedef __attribute__((ext_vector_type(8)))  __bf16          bf16x8;
typedef __attribute__((ext_vector_type(4)))  float           f32x4;
typedef __attribute__((ext_vector_type(8)))  unsigned short  ushort8_t;
typedef __attribute__((ext_vector_type(4)))  float           float4_t;

__device__ __forceinline__ unsigned short f2bf(float f) {
  return __builtin_bit_cast(unsigned short, static_cast<__bf16>(f));  // RNE
}
__device__ __forceinline__ float bf2f(unsigned short u) {
  unsigned int x = ((unsigned int)u) << 16;
  return __builtin_bit_cast(float, x);
}
__device__ __forceinline__ ushort8_t pack8(float4_t a, float4_t b) {
  ushort8_t r;
  r[0] = f2bf(a[0]); r[1] = f2bf(a[1]); r[2] = f2bf(a[2]); r[3] = f2bf(a[3]);
  r[4] = f2bf(b[0]); r[5] = f2bf(b[1]); r[6] = f2bf(b[2]); r[7] = f2bf(b[3]);
  return r;
}
__device__ __forceinline__ bf16x8 ldsfrag(const unsigned short* p) {
  return __builtin_bit_cast(bf16x8, *reinterpret_cast<const ushort8_t*>(p));
}

// Raw barrier: LDS writes committed, but global loads stay IN FLIGHT across
// it (counted vmcnt, not vmcnt(0) — the point vs __syncthreads).
__device__ __forceinline__ void barrier_lgkm() {
  asm volatile("s_waitcnt lgkmcnt(0)" ::: "memory");
  __builtin_amdgcn_s_barrier();
}

// LDS row stride 40 bf16 (80 B): 16B-granule g = 5*row + k16; both frag reads
// (rows base+fr) and staging writes hit each bank-group exactly 8x/wave (min).
#define LDK 40

// XCD-aware bijective swizzle (grid % 8 == 0): contiguous chunk per XCD.
__device__ __forceinline__ int xcd_swizzle(int bid, int nwg) {
  return (bid & 7) * (nwg >> 3) + (bid >> 3);
}

// ---------------------------------------------------------------------------
// Phase 1: H = bf16( silu(X@W1^T) * (X@W3^T) ), per expert.
// BM=256 x BN=64(per-mat), BK=32, 4 waves (2Mx2N), wave 128x32 DUAL.
// Per wave-K32: 12 ds_read_b128 -> 32 MFMA(16x16x32): LDS-duty ceiling 0.54.
// Reg ledger: acc 8*2*2*4=128 + staging 48*2=96 + addr ~16 = 240 <= 256 cap
// (launch_bounds(256,2)) -> NO SPILL (verify: WRITE_SIZE ~65 MB).
// Depth-2 reg prefetch + raw barriers (counted vmcnt(6) steady state).
// ---------------------------------------------------------------------------
#define P1_NKT (DIM / 32)

__global__ __launch_bounds__(256, 2) void p1_kernel(
    const float* __restrict__ X, const float* __restrict__ W1,
    const float* __restrict__ W3, unsigned short* __restrict__ H) {
  __shared__ __align__(16) unsigned short lA [2][256 * LDK];  // 40960 B
  __shared__ __align__(16) unsigned short lB1[2][ 64 * LDK];  // 10240 B
  __shared__ __align__(16) unsigned short lB3[2][ 64 * LDK];  // 10240 B

  const int tile = xcd_swizzle(blockIdx.x, NE * 4 * 8);  // 2048 blocks
  const int e  = tile >> 5;
  const int tn = (tile >> 2) & 7;    // 8 hid tiles of 64
  const int tm = tile & 3;           // inner: W1/W3 slab stays L2-hot
  const int t  = threadIdx.x;

  const float* gA  = X  + (size_t)(e * TPE + tm * 256) * DIM;
  const float* gB1 = W1 + ((size_t)e * HID + tn * 64) * DIM;
  const float* gB3 = W3 + ((size_t)e * HID + tn * 64) * DIM;

  // chunk c = 8 consecutive floats at (row c>>2, col (c&3)*8); lanes 4k..4k+3
  // cover one 128-B row segment (coalesced). A: 4 chunks/thr, B1/B3: 1 each.
  const int ar = t >> 2, ac = (t & 3) * 8;

  // depth-2: two NAMED register sets (static indexing — no scratch)
  float4_t a0[4][2], b10[2], b30[2];
  float4_t a1[4][2], b11[2], b31[2];

  auto load_g = [&](float4_t (&a)[4][2], float4_t (&b1)[2], float4_t (&b3)[2],
                    int kt) {
#pragma unroll
    for (int i = 0; i < 4; ++i) {
      const size_t o = (size_t)(ar + 64 * i) * DIM + kt * 32 + ac;
      a[i][0] = *reinterpret_cast<const float4_t*>(gA + o);
      a[i][1] = *reinterpret_cast<const float4_t*>(gA + o + 4);
    }
    const size_t ob = (size_t)ar * DIM + kt * 32 + ac;
    b1[0] = *reinterpret_cast<const float4_t*>(gB1 + ob);
    b1[1] = *reinterpret_cast<const float4_t*>(gB1 + ob + 4);
    b3[0] = *reinterpret_cast<const float4_t*>(gB3 + ob);
    b3[1] = *reinterpret_cast<const float4_t*>(gB3 + ob + 4);
  };
  auto store_l = [&](int buf, float4_t (&a)[4][2], float4_t (&b1)[2],
                     float4_t (&b3)[2]) {
#pragma unroll
    for (int i = 0; i < 4; ++i)
      *reinterpret_cast<ushort8_t*>(&lA[buf][(ar + 64 * i) * LDK + ac]) =
          pack8(a[i][0], a[i][1]);
    *reinterpret_cast<ushort8_t*>(&lB1[buf][ar * LDK + ac]) = pack8(b1[0], b1[1]);
    *reinterpret_cast<ushort8_t*>(&lB3[buf][ar * LDK + ac]) = pack8(b3[0], b3[1]);
  };

  const int lane = t & 63;
  const int wv   = t >> 6;
  const int wr   = wv >> 1, wc = wv & 1;   // 2x2 waves: 128M x 32N each
  const int fr   = lane & 15;
  const int ks   = (lane >> 4) * 8;        // k offset (8 bf16)

  f32x4 acc1[8][2], acc3[8][2];            // 128 regs (AGPR side)
#pragma unroll
  for (int m = 0; m < 8; ++m)
#pragma unroll
    for (int n = 0; n < 2; ++n)
#pragma unroll
      for (int i = 0; i < 4; ++i) { acc1[m][n][i] = 0.f; acc3[m][n][i] = 0.f; }

  auto mfma_phase = [&](int buf) {
    bf16x8 b1f[2], b3f[2];
#pragma unroll
    for (int n = 0; n < 2; ++n) {
      const int bi = (wc * 32 + n * 16 + fr) * LDK + ks;
      b1f[n] = ldsfrag(&lB1[buf][bi]);
      b3f[n] = ldsfrag(&lB3[buf][bi]);
    }
#pragma unroll
    for (int m = 0; m < 8; ++m) {
      const bf16x8 af = ldsfrag(&lA[buf][(wr * 128 + m * 16 + fr) * LDK + ks]);
#pragma unroll
      for (int n = 0; n < 2; ++n) {
        acc1[m][n] = __builtin_amdgcn_mfma_f32_16x16x32_bf16(af, b1f[n], acc1[m][n], 0, 0, 0);
        acc3[m][n] = __builtin_amdgcn_mfma_f32_16x16x32_bf16(af, b3f[n], acc3[m][n], 0, 0, 0);
      }
    }
  };

  load_g(a0, b10, b30, 0);
  load_g(a1, b11, b31, 1);
  for (int kt = 0; kt < P1_NKT; kt += 2) {
    store_l(0, a0, b10, b30);              // counted vmcnt: set-1 stays in flight
    if (kt + 2 < P1_NKT) load_g(a0, b10, b30, kt + 2);
    barrier_lgkm();                        // NO vmcnt drain
    mfma_phase(0);
    store_l(1, a1, b11, b31);
    if (kt + 3 < P1_NKT) load_g(a1, b11, b31, kt + 3);
    barrier_lgkm();
    mfma_phase(1);
  }

  // epilogue: silu(a)*b. 16x16 C/D: col=lane&15, row=(lane>>4)*4+reg [m89]
  const int tokBase = e * TPE + tm * 256 + wr * 128 + (lane >> 4) * 4;
  const int hidBase = tn * 64 + wc * 32;
#pragma unroll
  for (int m = 0; m < 8; ++m)
#pragma unroll
    for (int n = 0; n < 2; ++n)
#pragma unroll
      for (int r = 0; r < 4; ++r) {
        const int tok = tokBase + m * 16 + r;
        const int hid = hidBase + n * 16 + fr;
        const float av = bf2f(f2bf(acc1[m][n][r]));  // ref bf16 rounding
        const float bv = bf2f(f2bf(acc3[m][n][r]));
        const float s  = av / (1.0f + __expf(-av));
        H[(size_t)tok * HID + hid] = f2bf(s * bv);
      }
}

// ---------------------------------------------------------------------------
// Phase 2: OUT = fp32( bf16( H @ W2^T ) ), per expert.
// BM=256 x BN=128, BK=32, 4 waves (2Mx2N), wave 128x64 single.
// Per wave-K32: 12 ds_read_b128 -> 32 MFMA. Reg ledger: 128+64+16 = 208.
// ---------------------------------------------------------------------------
#define P2_NKT (HID / 32)

__global__ __launch_bounds__(256, 2) void p2_kernel(
    const unsigned short* __restrict__ Hin, const float* __restrict__ W2,
    float* __restrict__ OUT) {
  __shared__ __align__(16) unsigned short lA[2][256 * LDK];  // 40960 B
  __shared__ __align__(16) unsigned short lB[2][128 * LDK];  // 20480 B

  const int tile = xcd_swizzle(blockIdx.x, NE * 4 * 8);  // 2048 blocks
  const int e  = tile >> 5;
  const int tn = (tile >> 2) & 7;    // 8 dim tiles of 128
  const int tm = tile & 3;           // inner: W2 slab L2-hot
  const int t  = threadIdx.x;

  const unsigned short* gA = Hin + (size_t)(e * TPE + tm * 256) * HID;
  const float*          gB = W2  + ((size_t)e * DIM + tn * 128) * HID;

  // A (bf16): 256x32 sh -> 4 ushort8 chunks/thr at (row c>>2, col (c&3)*8)
  // B (fp32): 128x32 fl -> 2 chunks of 8 fl/thr at (row c>>2, col (c&3)*8)
  const int ar = t >> 2, ac = (t & 3) * 8;

  ushort8_t ha0[4], ha1[4];
  float4_t  wb0[2][2], wb1[2][2];

  auto load_g = [&](ushort8_t (&ha)[4], float4_t (&wb)[2][2], int kt) {
#pragma unroll
    for (int i = 0; i < 4; ++i)
      ha[i] = *reinterpret_cast<const ushort8_t*>(
          gA + (size_t)(ar + 64 * i) * HID + kt * 32 + ac);
#pragma unroll
    for (int i = 0; i < 2; ++i) {
      const size_t bo = (size_t)(ar + 64 * i) * HID + kt * 32 + ac;
      wb[i][0] = *reinterpret_cast<const float4_t*>(gB + bo);
      wb[i][1] = *reinterpret_cast<const float4_t*>(gB + bo + 4);
    }
  };
  auto store_l = [&](int buf, ushort8_t (&ha)[4], float4_t (&wb)[2][2]) {
#pragma unroll
    for (int i = 0; i < 4; ++i)
      *reinterpret_cast<ushort8_t*>(&lA[buf][(ar + 64 * i) * LDK + ac]) = ha[i];
#pragma unroll
    for (int i = 0; i < 2; ++i)
      *reinterpret_cast<ushort8_t*>(&lB[buf][(ar + 64 * i) * LDK + ac]) =
          pack8(wb[i][0], wb[i][1]);
  };

  const int lane = t & 63;
  const int wv   = t >> 6;
  const int wr   = wv >> 1, wc = wv & 1;   // 2x2 waves: 128M x 64N each
  const int fr   = lane & 15;
  const int ks   = (lane >> 4) * 8;

  f32x4 acc[8][4];                         // 128 regs
#pragma unroll
  for (int m = 0; m < 8; ++m)
#pragma unroll
    for (int n = 0; n < 4; ++n)
#pragma unroll
      for (int i = 0; i < 4; ++i) acc[m][n][i] = 0.f;

  auto mfma_phase = [&](int buf) {
    bf16x8 bfr[4];
#pragma unroll
    for (int n = 0; n < 4; ++n)
      bfr[n] = ldsfrag(&lB[buf][(wc * 64 + n * 16 + fr) * LDK + ks]);
#pragma unroll
    for (int m = 0; m < 8; ++m) {
      const bf16x8 af = ldsfrag(&lA[buf][(wr * 128 + m * 16 + fr) * LDK + ks]);
#pragma unroll
      for (int n = 0; n < 4; ++n)
        acc[m][n] = __builtin_amdgcn_mfma_f32_16x16x32_bf16(af, bfr[n], acc[m][n], 0, 0, 0);
    }
  };

  load_g(ha0, wb0, 0);
  load_g(ha1, wb1, 1);
  for (int kt = 0; kt < P2_NKT; kt += 2) {
    store_l(0, ha0, wb0);
    if (kt + 2 < P2_NKT) load_g(ha0, wb0, kt + 2);
    barrier_lgkm();
    mfma_phase(0);
    store_l(1, ha1, wb1);
    if (kt + 3 < P2_NKT) load_g(ha1, wb1, kt + 3);
    barrier_lgkm();
    mfma_phase(1);
  }

  const int tokBase = e * TPE + tm * 256 + wr * 128 + (lane >> 4) * 4;
  const int dBase   = tn * 128 + wc * 64;
#pragma unroll
  for (int m = 0; m < 8; ++m)
#pragma unroll
    for (int n = 0; n < 4; ++n)
#pragma unroll
      for (int r = 0; r < 4; ++r) {
        const int tok = tokBase + m * 16 + r;
        const int d   = dBase + n * 16 + fr;
        OUT[(size_t)tok * DIM + d] = bf2f(f2bf(acc[m][n][r]));  // ref bf16->f32
      }
}

// ---------------------------------------------------------------------------
extern "C" void kernel_launch(void* const* d_in, const int* in_sizes, int n_in,
                              void* d_out, int out_size, void* d_ws, size_t ws_size,
                              hipStream_t stream) {
  (void)in_sizes; (void)n_in; (void)out_size; (void)ws_size;
  const float* X  = (const float*)d_in[0];
  const float* W1 = (const float*)d_in[1];
  const float* W2 = (const float*)d_in[2];
  const float* W3 = (const float*)d_in[3];
  // d_in[4] = num_tokens_per_expert: uniform 1024/expert in this problem.

  unsigned short* H = (unsigned short*)d_ws;   // 65536 x 512 bf16 = 64 MiB
  float* OUT = (float*)d_out;

  p1_kernel<<<dim3(NE * 4 * 8), dim3(256), 0, stream>>>(X, W1, W3, H);
  p2_kernel<<<dim3(NE * 4 * 8), dim3(256), 0, stream>>>(H, W2, OUT);
}

// Round 7
// 438.025 us; speedup vs baseline: 1.1877x; 1.1814x over previous
//
#include <hip/hip_runtime.h>
#include <hip/hip_bf16.h>
#include <stdint.h>

#define NE   64
#define DIM  1024
#define HID  512
#define TPE  1024   // tokens per expert (uniform in this problem)

typedef __attribute__((ext_vector_type(8)))  __bf16          bf16x8;
typedef __attribute__((ext_vector_type(16))) float           f32x16;
typedef __attribute__((ext_vector_type(8)))  unsigned short  ushort8_t;
typedef __attribute__((ext_vector_type(4)))  float           float4_t;

__device__ __forceinline__ unsigned short f2bf(float f) {
  return __builtin_bit_cast(unsigned short, static_cast<__bf16>(f));  // RNE
}
__device__ __forceinline__ float bf2f(unsigned short u) {
  unsigned int x = ((unsigned int)u) << 16;
  return __builtin_bit_cast(float, x);
}
__device__ __forceinline__ ushort8_t pack8(float4_t a, float4_t b) {
  ushort8_t r;
  r[0] = f2bf(a[0]); r[1] = f2bf(a[1]); r[2] = f2bf(a[2]); r[3] = f2bf(a[3]);
  r[4] = f2bf(b[0]); r[5] = f2bf(b[1]); r[6] = f2bf(b[2]); r[7] = f2bf(b[3]);
  return r;
}
__device__ __forceinline__ bf16x8 ldsfrag(const unsigned short* p) {
  return __builtin_bit_cast(bf16x8, *reinterpret_cast<const ushort8_t*>(p));
}

// Raw barrier: LDS writes committed (lgkmcnt 0), global loads stay IN FLIGHT
// (counted vmcnt via register deps — never a vmcnt(0) drain in the loop).
__device__ __forceinline__ void barrier_lgkm() {
  asm volatile("s_waitcnt lgkmcnt(0)" ::: "memory");
  __builtin_amdgcn_s_barrier();
}

// LDS row stride 40 bf16 (80 B = 5 granules of 16 B): granule (5r + c) mod 8
// is uniform (8 lanes/slot = hw minimum) for both the frag-read pattern
// (rows base+lr, lr=lane&31) and the staging-write pattern (rows t>>2).
#define LDK 40

// XCD-aware bijective swizzle (grid % 8 == 0): contiguous chunk per XCD.
__device__ __forceinline__ int xcd_swizzle(int bid, int nwg) {
  return (bid & 7) * (nwg >> 3) + (bid >> 3);
}

// ---------------------------------------------------------------------------
// Phase 1: H = bf16( silu(X@W1^T) * (X@W3^T) ), per expert.
// KEY RESTRUCTURE: B-tile = [64 W1-rows ; 64 W3-rows] stacked -> SINGLE-acc
// GEMM 128x128. Wave = 32M x 128N (4 waves tile M): same lane holds the
// a-part (frags n=0,1) and b-part (n=2,3) of each hid channel -> register-
// local silu combine, no dual acc, no exchange.
// acc = 4 x f32x16 = 64 regs; A(X) depth-2 reg prefetch (HBM latency),
// B(W) depth-1 (L2-hot: tm is inner grid index + XCD swizzle).
// Per wave-kt: 10 ds_read_b128 -> 8 MFMA 32x32x16 (512 CU-cy vs ~364 LDS-cy).
// ---------------------------------------------------------------------------
#define P1_NKT (DIM / 32)

__global__ __launch_bounds__(256, 3) void p1_kernel(
    const float* __restrict__ X, const float* __restrict__ W1,
    const float* __restrict__ W3, unsigned short* __restrict__ H) {
  __shared__ __align__(16) unsigned short lA[2][128 * LDK];  // 20480 B
  __shared__ __align__(16) unsigned short lB[2][128 * LDK];  // 20480 B

  const int tile = xcd_swizzle(blockIdx.x, NE * 8 * 8);
  const int e  = tile >> 6;
  const int tn = (tile >> 3) & 7;    // 8 hid tiles of 64
  const int tm = tile & 7;           // inner: W1/W3 slab L2-hot
  const int t  = threadIdx.x;

  const float* gA  = X  + (size_t)(e * TPE + tm * 128) * DIM;
  const float* gW1 = W1 + ((size_t)e * HID + tn * 64) * DIM;
  const float* gW3 = W3 + ((size_t)e * HID + tn * 64) * DIM;

  // chunks of 8 floats: row t>>2 (+64 for 2nd chunk), cols (t&3)*8 — lanes
  // 4k..4k+3 cover one 128-B row segment (coalesced).
  const int ar = t >> 2, ac = (t & 3) * 8;

  float4_t a0[2][2], a1[2][2];   // A depth-2: X rows ar, ar+64
  float4_t bb[2][2];             // B depth-1: bb[0]=W1 row ar, bb[1]=W3 row ar

  auto load_gA = [&](float4_t (&a)[2][2], int kt) {
#pragma unroll
    for (int i = 0; i < 2; ++i) {
      const size_t o = (size_t)(ar + 64 * i) * DIM + kt * 32 + ac;
      a[i][0] = *reinterpret_cast<const float4_t*>(gA + o);
      a[i][1] = *reinterpret_cast<const float4_t*>(gA + o + 4);
    }
  };
  auto load_gB = [&](int kt) {
    const size_t o = (size_t)ar * DIM + kt * 32 + ac;
    bb[0][0] = *reinterpret_cast<const float4_t*>(gW1 + o);
    bb[0][1] = *reinterpret_cast<const float4_t*>(gW1 + o + 4);
    bb[1][0] = *reinterpret_cast<const float4_t*>(gW3 + o);
    bb[1][1] = *reinterpret_cast<const float4_t*>(gW3 + o + 4);
  };
  auto store_lA = [&](int buf, float4_t (&a)[2][2]) {
#pragma unroll
    for (int i = 0; i < 2; ++i)
      *reinterpret_cast<ushort8_t*>(&lA[buf][(ar + 64 * i) * LDK + ac]) =
          pack8(a[i][0], a[i][1]);
  };
  auto store_lB = [&](int buf) {
    *reinterpret_cast<ushort8_t*>(&lB[buf][ar * LDK + ac]) = pack8(bb[0][0], bb[0][1]);
    *reinterpret_cast<ushort8_t*>(&lB[buf][(ar + 64) * LDK + ac]) = pack8(bb[1][0], bb[1][1]);
  };

  const int lane = t & 63;
  const int wv   = t >> 6;           // wave's 32-row M block
  const int lr   = lane & 31;
  const int ks   = (lane >> 5) * 8;  // k half (8 bf16)

  f32x16 acc[4];                     // n=0,1: W1-part; n=2,3: W3-part (64 regs)
#pragma unroll
  for (int n = 0; n < 4; ++n)
#pragma unroll
    for (int i = 0; i < 16; ++i) acc[n][i] = 0.f;

  auto mfma_phase = [&](int buf) {
#pragma unroll
    for (int kk = 0; kk < 2; ++kk) {
      const bf16x8 af = ldsfrag(&lA[buf][(wv * 32 + lr) * LDK + kk * 16 + ks]);
#pragma unroll
      for (int n = 0; n < 4; ++n) {
        const bf16x8 bf = ldsfrag(&lB[buf][(n * 32 + lr) * LDK + kk * 16 + ks]);
        acc[n] = __builtin_amdgcn_mfma_f32_32x32x16_bf16(af, bf, acc[n], 0, 0, 0);
      }
    }
  };

  load_gA(a0, 0);
  load_gB(0);
  load_gA(a1, 1);
  for (int kt = 0; kt < P1_NKT; kt += 2) {
    store_lA(0, a0); store_lB(0);          // counted vmcnt (a1 + next B fly)
    if (kt + 2 < P1_NKT) load_gA(a0, kt + 2);
    load_gB(kt + 1);                        // kt+1 <= NKT-1 always
    barrier_lgkm();                         // NO vmcnt drain
    mfma_phase(0);

    store_lA(1, a1); store_lB(1);
    if (kt + 3 < P1_NKT) load_gA(a1, kt + 3);
    if (kt + 2 < P1_NKT) load_gB(kt + 2);
    barrier_lgkm();
    mfma_phase(1);
  }

  // epilogue: register-local combine. 32x32 C/D: col=lane&31,
  // row=(r&3)+8*(r>>2)+4*(lane>>5)  [m74/m101]
  const int tokBase = e * TPE + tm * 128 + wv * 32;
  const int hidBase = tn * 64;
  const int ks4     = (lane >> 5) * 4;
#pragma unroll
  for (int n = 0; n < 2; ++n)
#pragma unroll
    for (int r = 0; r < 16; ++r) {
      const int rr  = (r & 3) + 8 * (r >> 2) + ks4;
      const int tok = tokBase + rr;
      const int hid = hidBase + n * 32 + lr;
      const float av = bf2f(f2bf(acc[n][r]));      // ref bf16 rounding
      const float bv = bf2f(f2bf(acc[n + 2][r]));
      const float s  = av / (1.0f + __expf(-av));
      H[(size_t)tok * HID + hid] = f2bf(s * bv);
    }
}

// ---------------------------------------------------------------------------
// Phase 2: OUT = fp32( bf16( H @ W2^T ) ), per expert.
// Same machinery: BM=128, BN=128, wave 32x128, acc[4]=64 regs.
// A = H (already bf16: plain copy staging, depth-2); B = W2 (depth-1, L2-hot).
// ---------------------------------------------------------------------------
#define P2_NKT (HID / 32)

__global__ __launch_bounds__(256, 3) void p2_kernel(
    const unsigned short* __restrict__ Hin, const float* __restrict__ W2,
    float* __restrict__ OUT) {
  __shared__ __align__(16) unsigned short lA[2][128 * LDK];  // 20480 B
  __shared__ __align__(16) unsigned short lB[2][128 * LDK];  // 20480 B

  const int tile = xcd_swizzle(blockIdx.x, NE * 8 * 8);
  const int e  = tile >> 6;
  const int tn = (tile >> 3) & 7;    // 8 dim tiles of 128
  const int tm = tile & 7;           // inner: W2 slab L2-hot
  const int t  = threadIdx.x;

  const unsigned short* gA = Hin + (size_t)(e * TPE + tm * 128) * HID;
  const float*          gB = W2  + ((size_t)e * DIM + tn * 128) * HID;

  const int ar = t >> 2, ac = (t & 3) * 8;

  ushort8_t ha0[2], ha1[2];          // A depth-2 (bf16 plain copy)
  float4_t  wb[2][2];                // B depth-1 (fp32 -> cvt)

  auto load_gA = [&](ushort8_t (&ha)[2], int kt) {
#pragma unroll
    for (int i = 0; i < 2; ++i)
      ha[i] = *reinterpret_cast<const ushort8_t*>(
          gA + (size_t)(ar + 64 * i) * HID + kt * 32 + ac);
  };
  auto load_gB = [&](int kt) {
#pragma unroll
    for (int i = 0; i < 2; ++i) {
      const size_t o = (size_t)(ar + 64 * i) * HID + kt * 32 + ac;
      wb[i][0] = *reinterpret_cast<const float4_t*>(gB + o);
      wb[i][1] = *reinterpret_cast<const float4_t*>(gB + o + 4);
    }
  };
  auto store_lA = [&](int buf, ushort8_t (&ha)[2]) {
#pragma unroll
    for (int i = 0; i < 2; ++i)
      *reinterpret_cast<ushort8_t*>(&lA[buf][(ar + 64 * i) * LDK + ac]) = ha[i];
  };
  auto store_lB = [&](int buf) {
#pragma unroll
    for (int i = 0; i < 2; ++i)
      *reinterpret_cast<ushort8_t*>(&lB[buf][(ar + 64 * i) * LDK + ac]) =
          pack8(wb[i][0], wb[i][1]);
  };

  const int lane = t & 63;
  const int wv   = t >> 6;
  const int lr   = lane & 31;
  const int ks   = (lane >> 5) * 8;

  f32x16 acc[4];
#pragma unroll
  for (int n = 0; n < 4; ++n)
#pragma unroll
    for (int i = 0; i < 16; ++i) acc[n][i] = 0.f;

  auto mfma_phase = [&](int buf) {
#pragma unroll
    for (int kk = 0; kk < 2; ++kk) {
      const bf16x8 af = ldsfrag(&lA[buf][(wv * 32 + lr) * LDK + kk * 16 + ks]);
#pragma unroll
      for (int n = 0; n < 4; ++n) {
        const bf16x8 bf = ldsfrag(&lB[buf][(n * 32 + lr) * LDK + kk * 16 + ks]);
        acc[n] = __builtin_amdgcn_mfma_f32_32x32x16_bf16(af, bf, acc[n], 0, 0, 0);
      }
    }
  };

  load_gA(ha0, 0);
  load_gB(0);
  load_gA(ha1, 1);
  for (int kt = 0; kt < P2_NKT; kt += 2) {
    store_lA(0, ha0); store_lB(0);
    if (kt + 2 < P2_NKT) load_gA(ha0, kt + 2);
    load_gB(kt + 1);
    barrier_lgkm();
    mfma_phase(0);

    store_lA(1, ha1); store_lB(1);
    if (kt + 3 < P2_NKT) load_gA(ha1, kt + 3);
    if (kt + 2 < P2_NKT) load_gB(kt + 2);
    barrier_lgkm();
    mfma_phase(1);
  }

  const int tokBase = e * TPE + tm * 128 + wv * 32;
  const int dBase   = tn * 128;
  const int ks4     = (lane >> 5) * 4;
#pragma unroll
  for (int n = 0; n < 4; ++n)
#pragma unroll
    for (int r = 0; r < 16; ++r) {
      const int rr  = (r & 3) + 8 * (r >> 2) + ks4;
      const int tok = tokBase + rr;
      const int d   = dBase + n * 32 + lr;
      OUT[(size_t)tok * DIM + d] = bf2f(f2bf(acc[n][r]));  // ref bf16->f32
    }
}

// ---------------------------------------------------------------------------
extern "C" void kernel_launch(void* const* d_in, const int* in_sizes, int n_in,
                              void* d_out, int out_size, void* d_ws, size_t ws_size,
                              hipStream_t stream) {
  (void)in_sizes; (void)n_in; (void)out_size; (void)ws_size;
  const float* X  = (const float*)d_in[0];
  const float* W1 = (const float*)d_in[1];
  const float* W2 = (const float*)d_in[2];
  const float* W3 = (const float*)d_in[3];
  // d_in[4] = num_tokens_per_expert: uniform 1024/expert in this problem.

  unsigned short* H = (unsigned short*)d_ws;   // 65536 x 512 bf16 = 64 MiB
  float* OUT = (float*)d_out;

  p1_kernel<<<dim3(NE * 8 * 8), dim3(256), 0, stream>>>(X, W1, W3, H);
  p2_kernel<<<dim3(NE * 8 * 8), dim3(256), 0, stream>>>(H, W2, OUT);
}